// Round 1
// baseline (1179.680 us; speedup 1.0000x reference)
//
#include <hip/hip_runtime.h>

// FusedGromovWasserstein — fully fused, one block (256 thr) per batch.
// B=8192, K=M=16, D=256. eps=clip(exp(log_eps),.01,.5), rho=0.1/(0.1+eps).
// Projection: split-bf16 (hi/lo) 3-product MFMA emulation of f32 GEMM.
// Outputs flat: [sigmoid(-cost) 8192][T 8192*256][C 8192*256][cost 8192].

#define OFF_T   8192
#define OFF_C   2105344
#define OFF_CST 4202496

typedef float  f32x4 __attribute__((ext_vector_type(4)));
typedef short  s16x8 __attribute__((ext_vector_type(8)));

__device__ __forceinline__ unsigned short f2bf(float f) {
  unsigned int u = __float_as_uint(f);
  u += 0x7FFFu + ((u >> 16) & 1u);          // round-to-nearest-even
  return (unsigned short)(u >> 16);
}
__device__ __forceinline__ float bf2f(unsigned short h) {
  return __uint_as_float(((unsigned int)h) << 16);
}
__device__ __forceinline__ float rsum16(float x) {
  x += __shfl_xor(x, 1); x += __shfl_xor(x, 2);
  x += __shfl_xor(x, 4); x += __shfl_xor(x, 8);
  return x;
}
__device__ __forceinline__ float rmax16(float x) {
  x = fmaxf(x, __shfl_xor(x, 1)); x = fmaxf(x, __shfl_xor(x, 2));
  x = fmaxf(x, __shfl_xor(x, 4)); x = fmaxf(x, __shfl_xor(x, 8));
  return x;
}

// LDS map (bytes):
//   [0,16384)      x_hi [32 rows][256 k] bf16, row stride 512B, XOR-swizzled
//   [16384,32768)  x_lo (same layout)           (h overwrites x between layers)
//   [32768,49152)  wc_hi [256 cols][32 k] bf16  (B^T form, linear)
//   [49152,65536)  wc_lo
//   p f32 [32][260] overlays [0,33280) after projection
//   sinkhorn scratch overlays bytes 34048.. (inside dead wc region)
__global__ __launch_bounds__(256, 2)
void fgw_fused(const float* __restrict__ g_q,  const float* __restrict__ g_r,
               const float* __restrict__ g_mq, const float* __restrict__ g_mr,
               const float* __restrict__ g_cq, const float* __restrict__ g_cr,
               const float* __restrict__ g_W1, const float* __restrict__ g_b1,
               const float* __restrict__ g_W2, const float* __restrict__ g_b2,
               const float* __restrict__ g_leps, float* __restrict__ g_out)
{
  __shared__ __align__(16) float smemf[16384];   // 64 KB
  char* sm = (char*)smemf;
  const int bId  = blockIdx.x;
  const int tid  = threadIdx.x;
  const int lane = tid & 63, wid = tid >> 6;
  const int fr   = lane & 15, fg = lane >> 4;

  // ---------------- stage slots (q rows 0-15, r rows 16-31) as hi/lo bf16 ----
  {
    const float* xq = g_q + (size_t)bId * 4096;
    const float* xr = g_r + (size_t)bId * 4096;
    #pragma unroll
    for (int j = 0; j < 4; ++j) {
      int idx = (j << 8) + tid;          // 0..1023
      int r   = idx >> 6;                // row 0..15
      int sg  = idx & 63;                // float4 segment
      int off = ((sg << 3) ^ ((r & 7) << 4));
      float4 v0 = *(const float4*)(xq + (r << 8) + (sg << 2));
      float4 v1 = *(const float4*)(xr + (r << 8) + (sg << 2));
      {
        unsigned short a = f2bf(v0.x), b = f2bf(v0.y), c = f2bf(v0.z), d = f2bf(v0.w);
        unsigned int* ph = (unsigned int*)(sm + r * 512 + off);
        ph[0] = (unsigned)a | ((unsigned)b << 16);
        ph[1] = (unsigned)c | ((unsigned)d << 16);
        unsigned short la = f2bf(v0.x - bf2f(a)), lb = f2bf(v0.y - bf2f(b));
        unsigned short lc = f2bf(v0.z - bf2f(c)), ld = f2bf(v0.w - bf2f(d));
        unsigned int* pl = (unsigned int*)(sm + 16384 + r * 512 + off);
        pl[0] = (unsigned)la | ((unsigned)lb << 16);
        pl[1] = (unsigned)lc | ((unsigned)ld << 16);
      }
      {
        int r2 = 16 + r;                 // same (row&7) -> same swizzle
        unsigned short a = f2bf(v1.x), b = f2bf(v1.y), c = f2bf(v1.z), d = f2bf(v1.w);
        unsigned int* ph = (unsigned int*)(sm + r2 * 512 + off);
        ph[0] = (unsigned)a | ((unsigned)b << 16);
        ph[1] = (unsigned)c | ((unsigned)d << 16);
        unsigned short la = f2bf(v1.x - bf2f(a)), lb = f2bf(v1.y - bf2f(b));
        unsigned short lc = f2bf(v1.z - bf2f(c)), ld = f2bf(v1.w - bf2f(d));
        unsigned int* pl = (unsigned int*)(sm + 16384 + r2 * 512 + off);
        pl[0] = (unsigned)la | ((unsigned)lb << 16);
        pl[1] = (unsigned)lc | ((unsigned)ld << 16);
      }
    }
  }

  // ---------------- two projection layers: out = act(X @ W^T + b) -----------
  const float* Wl = g_W1;
  const float* bl = g_b1;
  for (int layer = 0; layer < 2; ++layer) {
    const f32x4 vzero = {0.f, 0.f, 0.f, 0.f};
    f32x4 acc[2][4];
    #pragma unroll
    for (int i = 0; i < 2; ++i) {
      #pragma unroll
      for (int j = 0; j < 4; ++j) acc[i][j] = vzero;
    }
    for (int ks = 0; ks < 8; ++ks) {
      const int k0 = ks << 5;
      // stage W chunk [256 cols][32 k] as hi/lo bf16 (f32 -> split on the fly)
      #pragma unroll
      for (int j = 0; j < 4; ++j) {
        int c  = (j << 6) + (tid >> 2);
        int kb = (tid & 3) << 3;
        const float* wr = Wl + ((size_t)c << 8) + k0 + kb;
        float4 wa = *(const float4*)wr;
        float4 wb = *(const float4*)(wr + 4);
        float fv[8] = {wa.x, wa.y, wa.z, wa.w, wb.x, wb.y, wb.z, wb.w};
        unsigned int uh[4], ul[4];
        #pragma unroll
        for (int i = 0; i < 4; ++i) {
          unsigned short h0 = f2bf(fv[2*i]),     h1 = f2bf(fv[2*i+1]);
          unsigned short l0 = f2bf(fv[2*i]   - bf2f(h0));
          unsigned short l1 = f2bf(fv[2*i+1] - bf2f(h1));
          uh[i] = (unsigned)h0 | ((unsigned)h1 << 16);
          ul[i] = (unsigned)l0 | ((unsigned)l1 << 16);
        }
        unsigned int* ph = (unsigned int*)(sm + 32768 + c * 64 + (kb << 1));
        unsigned int* pl = (unsigned int*)(sm + 49152 + c * 64 + (kb << 1));
        ph[0] = uh[0]; ph[1] = uh[1]; ph[2] = uh[2]; ph[3] = uh[3];
        pl[0] = ul[0]; pl[1] = ul[1]; pl[2] = ul[2]; pl[3] = ul[3];
      }
      __syncthreads();
      // A fragments (rows fr and 16+fr, 8 contiguous k at (lane>>4)*8)
      const int koff = (k0 << 1) + (fg << 4);
      const int aoff = koff ^ ((fr & 7) << 4);
      s16x8 ah0 = *(const s16x8*)(sm +          fr * 512      + aoff);
      s16x8 ah1 = *(const s16x8*)(sm +         (16 + fr) * 512 + aoff);
      s16x8 al0 = *(const s16x8*)(sm + 16384 +  fr * 512      + aoff);
      s16x8 al1 = *(const s16x8*)(sm + 16384 + (16 + fr) * 512 + aoff);
      #pragma unroll
      for (int nt = 0; nt < 4; ++nt) {
        const int cb = ((wid << 6) + (nt << 4) + fr) * 64 + (fg << 4);
        s16x8 bh  = *(const s16x8*)(sm + 32768 + cb);
        s16x8 blo = *(const s16x8*)(sm + 49152 + cb);
        // 3-product split: hi*hi + hi*lo + lo*hi (lo*lo dropped, ~2^-18)
        acc[0][nt] = __builtin_amdgcn_mfma_f32_16x16x32_bf16(ah0, bh,  acc[0][nt], 0, 0, 0);
        acc[1][nt] = __builtin_amdgcn_mfma_f32_16x16x32_bf16(ah1, bh,  acc[1][nt], 0, 0, 0);
        acc[0][nt] = __builtin_amdgcn_mfma_f32_16x16x32_bf16(ah0, blo, acc[0][nt], 0, 0, 0);
        acc[1][nt] = __builtin_amdgcn_mfma_f32_16x16x32_bf16(ah1, blo, acc[1][nt], 0, 0, 0);
        acc[0][nt] = __builtin_amdgcn_mfma_f32_16x16x32_bf16(al0, bh,  acc[0][nt], 0, 0, 0);
        acc[1][nt] = __builtin_amdgcn_mfma_f32_16x16x32_bf16(al1, bh,  acc[1][nt], 0, 0, 0);
      }
      __syncthreads();
    }
    // epilogue: D frag lane map (verified m89): row=(lane>>4)*4+reg, col=lane&15
    float bv[4];
    #pragma unroll
    for (int nt = 0; nt < 4; ++nt) bv[nt] = bl[(wid << 6) + (nt << 4) + fr];
    if (layer == 0) {
      #pragma unroll
      for (int mt = 0; mt < 2; ++mt) {
        #pragma unroll
        for (int nt = 0; nt < 4; ++nt) {
          #pragma unroll
          for (int j = 0; j < 4; ++j) {
            float h = fmaxf(acc[mt][nt][j] + bv[nt], 0.f);
            int row = (mt << 4) + (fg << 2) + j;
            int col = (wid << 6) + (nt << 4) + fr;
            int off = ((col << 1) ^ ((row & 7) << 4));
            unsigned short hh = f2bf(h);
            unsigned short hl = f2bf(h - bf2f(hh));
            *(unsigned short*)(sm +         row * 512 + off) = hh;
            *(unsigned short*)(sm + 16384 + row * 512 + off) = hl;
          }
        }
      }
      __syncthreads();
      Wl = g_W2; bl = g_b2;
    } else {
      float* p = (float*)sm;          // f32 [32][260]
      #pragma unroll
      for (int mt = 0; mt < 2; ++mt) {
        #pragma unroll
        for (int nt = 0; nt < 4; ++nt) {
          #pragma unroll
          for (int j = 0; j < 4; ++j) {
            int row = (mt << 4) + (fg << 2) + j;
            int col = (wid << 6) + (nt << 4) + fr;
            p[row * 260 + col] = acc[mt][nt][j] + bv[nt];
          }
        }
      }
      __syncthreads();
    }
  }

  // ---------------- sinkhorn scratch (overlays dead wc region) --------------
  float* sk   = smemf + 8512;                 // byte 34048
  float* Sq   = sk;        float* Sr   = sk + 272;
  float* Sq2  = sk + 544;  float* Sr2  = sk + 816;
  float* Tlm  = sk + 1088; float* Ttm  = sk + 1360;
  float* Mm   = sk + 1632; float* St   = sk + 1904;
  float* trow = sk + 2176; float* tcol = sk + 2192; float* vl = sk + 2208;
  float* mul_ = sk + 2224; float* nul_ = sk + 2240;
  float* lmu  = sk + 2256; float* lnu  = sk + 2272;
  float* cqx  = sk + 2288; float* cqy  = sk + 2304;
  float* crx  = sk + 2320; float* cry  = sk + 2336;
  float* red  = sk + 2352;

  if (tid < 32) {          // centroids + masks -> mu/nu, log mu/nu
    int i = tid & 15;
    const float* cc = (tid < 16 ? g_cq : g_cr) + (size_t)bId * 32 + (i << 1);
    float cx = cc[0], cy = cc[1];
    float mv = (tid < 16 ? g_mq : g_mr)[(size_t)bId * 16 + i];
    float s  = rsum16(mv);
    float muv = mv / (s + 1e-8f);
    float lg  = __logf(fmaxf(muv, 1e-8f));
    if (tid < 16) { cqx[i] = cx; cqy[i] = cy; mul_[i] = muv; lmu[i] = lg; }
    else          { crx[i] = cx; cry[i] = cy; nul_[i] = muv; lnu[i] = lg; }
  }

  // ---------------- C[k][m] = ||pq_k - pr_m|| (clamped like reference) ------
  const int tk = tid >> 4, tm = tid & 15;
  float C_reg;
  {
    const float* pq_ = (const float*)sm + tk * 260;
    const float* pr_ = (const float*)sm + (16 + tm) * 260;
    float d2 = 0.f;
    #pragma unroll 8
    for (int d = 0; d < 256; d += 4) {
      float4 a = *(const float4*)(pq_ + d);
      float4 c = *(const float4*)(pr_ + d);
      float e0 = a.x - c.x, e1 = a.y - c.y, e2 = a.z - c.z, e3 = a.w - c.w;
      d2 += e0 * e0 + e1 * e1 + e2 * e2 + e3 * e3;
    }
    C_reg = sqrtf(fmaxf(d2, 1e-6f));
  }
  __syncthreads();

  {  // Sq/Sr centroid distance matrices (clamp BEFORE sqrt, like reference)
    float dx = cqx[tk] - cqx[tm], dy = cqy[tk] - cqy[tm];
    float s1 = sqrtf(fmaxf(dx * dx + dy * dy, 1e-6f));
    Sq[tk * 17 + tm] = s1;  Sq2[tk * 17 + tm] = s1 * s1;
    float ex = crx[tk] - crx[tm], ey = cry[tk] - cry[tm];
    float s2 = sqrtf(fmaxf(ex * ex + ey * ey, 1e-6f));
    Sr[tk * 17 + tm] = s2;  Sr2[tk * 17 + tm] = s2 * s2;
  }
  float eps = __expf(g_leps[0]);
  eps = fminf(fmaxf(eps, 0.01f), 0.5f);
  const float inv_eps = 1.0f / eps;
  const float rho = 0.1f / (0.1f + eps);
  float T_reg = mul_[tk] * nul_[tm];
  Tlm[tk * 17 + tm] = T_reg;  Ttm[tm * 17 + tk] = T_reg;
  const float lmu_k = lmu[tk], lnu_k = lnu[tk];
  __syncthreads();

  // ---------------- 5 outer FGW iterations, 10 sinkhorn each ----------------
  float Cfgw = 0.f, logK = 0.f, u_reg = 0.f, v_reg = 0.f;
  for (int it = 0; it < 5; ++it) {
    float tr = rsum16(T_reg);                 // row sums of T
    float tc = rsum16(Ttm[tk * 17 + tm]);     // col sums of T
    if (tm == 0) { trow[tk] = tr; tcol[tk] = tc; }
    __syncthreads();
    float t1 = rsum16(Sq2[tk * 17 + tm] * trow[tm]);
    float t2 = 0.f;
    #pragma unroll
    for (int l = 0; l < 16; ++l) t2 += tcol[l] * Sr2[l * 17 + tm];
    float m1 = 0.f;
    #pragma unroll
    for (int l = 0; l < 16; ++l) m1 += Tlm[tk * 17 + l] * Sr[l * 17 + tm];
    Mm[tk * 17 + tm] = m1;
    __syncthreads();
    float t3 = 0.f;
    #pragma unroll
    for (int l = 0; l < 16; ++l) t3 += Sq[tk * 17 + l] * Mm[l * 17 + tm];
    Cfgw = 0.5f * C_reg + 0.5f * (t1 + t2 - 2.0f * t3);
    logK = -Cfgw * inv_eps;
    u_reg = 0.f; v_reg = 0.f;
    for (int s = 0; s < 10; ++s) {
      // log_u = rho*(log_mu - LSE_m(logK + v))   [within 16-lane group]
      float x  = logK + v_reg;
      float mx = rmax16(x);
      float lse = mx + __logf(rsum16(__expf(x - mx)));
      u_reg = rho * (lmu_k - lse);
      // log_v = rho*(log_nu - LSE_k(logK + u))   [via LDS transpose]
      St[tm * 17 + tk] = logK + u_reg;
      __syncthreads();
      float y  = St[tk * 17 + tm];
      float my = rmax16(y);
      float lse2 = my + __logf(rsum16(__expf(y - my)));
      if (tm == 0) vl[tk] = rho * (lnu_k - lse2);
      __syncthreads();
      v_reg = vl[tm];
    }
    T_reg = __expf(u_reg + logK + v_reg);
    Tlm[tk * 17 + tm] = T_reg;  Ttm[tm * 17 + tk] = T_reg;
    __syncthreads();
  }

  // ---------------- outputs -------------------------------------------------
  float cp = T_reg * Cfgw;
  cp += __shfl_xor(cp, 1);  cp += __shfl_xor(cp, 2);  cp += __shfl_xor(cp, 4);
  cp += __shfl_xor(cp, 8);  cp += __shfl_xor(cp, 16); cp += __shfl_xor(cp, 32);
  if (lane == 0) red[wid] = cp;
  __syncthreads();
  g_out[OFF_T + (size_t)bId * 256 + tid] = T_reg;
  g_out[OFF_C + (size_t)bId * 256 + tid] = C_reg;
  if (tid == 0) {
    float cost = red[0] + red[1] + red[2] + red[3];
    g_out[bId] = 1.0f / (1.0f + __expf(cost));   // sigmoid(-cost)
    g_out[OFF_CST + bId] = cost;
  }
}

extern "C" void kernel_launch(void* const* d_in, const int* in_sizes, int n_in,
                              void* d_out, int out_size, void* d_ws, size_t ws_size,
                              hipStream_t stream) {
  (void)in_sizes; (void)n_in; (void)out_size; (void)d_ws; (void)ws_size;
  fgw_fused<<<dim3(8192), dim3(256), 0, stream>>>(
      (const float*)d_in[0], (const float*)d_in[1],
      (const float*)d_in[2], (const float*)d_in[3],
      (const float*)d_in[4], (const float*)d_in[5],
      (const float*)d_in[6], (const float*)d_in[7],
      (const float*)d_in[8], (const float*)d_in[9],
      (const float*)d_in[10], (float*)d_out);
}

// Round 2
// 628.204 us; speedup vs baseline: 1.8779x; 1.8779x over previous
//
#include <hip/hip_runtime.h>

// FusedGromovWasserstein — 3 kernels:
//  prep_w:   W1,W2 f32 -> pre-split bf16 hi/lo MFMA B-fragments in d_ws (once per call)
//  fgw_proj: per-batch 2-layer MLP via split-bf16 MFMA + C = pdist(pq,pr) -> g_out[OFF_C]
//  fgw_sink: per-batch FGW outer loop + sinkhorn -> T, cost, sigmoid(-cost)
// B=8192, K=M=16, D=256.
// Outputs flat: [sigmoid(-cost) 8192][T 8192*256][C 8192*256][cost 8192].

#define OFF_T   8192
#define OFF_C   2105344
#define OFF_CST 4202496

typedef float  f32x4 __attribute__((ext_vector_type(4)));
typedef short  s16x8 __attribute__((ext_vector_type(8)));

__device__ __forceinline__ unsigned short f2bf(float f) {
  unsigned int u = __float_as_uint(f);
  u += 0x7FFFu + ((u >> 16) & 1u);          // round-to-nearest-even
  return (unsigned short)(u >> 16);
}
__device__ __forceinline__ float bf2f(unsigned short h) {
  return __uint_as_float(((unsigned int)h) << 16);
}
__device__ __forceinline__ float rsum16(float x) {
  x += __shfl_xor(x, 1); x += __shfl_xor(x, 2);
  x += __shfl_xor(x, 4); x += __shfl_xor(x, 8);
  return x;
}
__device__ __forceinline__ float rmax16(float x) {
  x = fmaxf(x, __shfl_xor(x, 1)); x = fmaxf(x, __shfl_xor(x, 2));
  x = fmaxf(x, __shfl_xor(x, 4)); x = fmaxf(x, __shfl_xor(x, 8));
  return x;
}

// ---------------------------------------------------------------------------
// prep_w: 16384 fragments (2 layers x 8 ksteps x 16 colgroups x 64 lanes), 8
// bf16 each. Fragment fid holds W[col=cg*16+fr][k = s*32 + fg*8 + e], so the
// main kernel's per-(kstep,colgroup) wave load is base + lane*16B (coalesced).
__global__ __launch_bounds__(256, 1)
void prep_w(const float* __restrict__ W1, const float* __restrict__ W2,
            unsigned int* __restrict__ wh, unsigned int* __restrict__ wl)
{
  const int fid  = blockIdx.x * 256 + threadIdx.x;   // 0..16383
  const int l    = fid >> 13;
  const int s    = (fid >> 10) & 7;
  const int cg   = (fid >> 6) & 15;
  const int lane = fid & 63;
  const int fr   = lane & 15, fg = lane >> 4;
  const int col  = cg * 16 + fr;
  const float* W = l ? W2 : W1;
  const float* src = W + ((size_t)col << 8) + (s << 5) + (fg << 3);
  float4 a = *(const float4*)src;
  float4 b = *(const float4*)(src + 4);
  float f[8] = {a.x, a.y, a.z, a.w, b.x, b.y, b.z, b.w};
  unsigned int uh[4], ul[4];
  #pragma unroll
  for (int i = 0; i < 4; ++i) {
    unsigned short h0 = f2bf(f[2*i]),            h1 = f2bf(f[2*i+1]);
    unsigned short l0 = f2bf(f[2*i]   - bf2f(h0));
    unsigned short l1 = f2bf(f[2*i+1] - bf2f(h1));
    uh[i] = (unsigned)h0 | ((unsigned)h1 << 16);
    ul[i] = (unsigned)l0 | ((unsigned)l1 << 16);
  }
  uint4 vh = {uh[0], uh[1], uh[2], uh[3]};
  uint4 vl = {ul[0], ul[1], ul[2], ul[3]};
  ((uint4*)wh)[fid] = vh;
  ((uint4*)wl)[fid] = vl;
}

// ---------------------------------------------------------------------------
// fgw_proj: one block per batch. LDS: x_hi [0,16384) / x_lo [16384,32768),
// rows 0-15 = q, 16-31 = r, row stride 512B, XOR-swizzled by ((row&7)<<4).
// After GEMM, p f32 [32][260] overlays everything. Zero barriers in k-loop.
__global__ __launch_bounds__(256, 4)
void fgw_proj(const float* __restrict__ g_q,  const float* __restrict__ g_r,
              const unsigned short* __restrict__ wh,
              const unsigned short* __restrict__ wl,
              const float* __restrict__ g_b1, const float* __restrict__ g_b2,
              float* __restrict__ g_out)
{
  __shared__ __align__(16) float smemf[8320];   // 33,280 B
  char* sm = (char*)smemf;
  const int bId  = blockIdx.x;
  const int tid  = threadIdx.x;
  const int lane = tid & 63, wid = tid >> 6;
  const int fr   = lane & 15, fg = lane >> 4;

  // ---- stage slots (q rows 0-15, r rows 16-31) as hi/lo bf16 ----
  {
    const float* xq = g_q + (size_t)bId * 4096;
    const float* xr = g_r + (size_t)bId * 4096;
    #pragma unroll
    for (int j = 0; j < 4; ++j) {
      int idx = (j << 8) + tid;          // 0..1023
      int r   = idx >> 6;                // row 0..15
      int sg  = idx & 63;                // float4 segment
      int off = ((sg << 3) ^ ((r & 7) << 4));
      float4 v0 = *(const float4*)(xq + (r << 8) + (sg << 2));
      float4 v1 = *(const float4*)(xr + (r << 8) + (sg << 2));
      {
        unsigned short a = f2bf(v0.x), b = f2bf(v0.y), c = f2bf(v0.z), d = f2bf(v0.w);
        unsigned int* ph = (unsigned int*)(sm + r * 512 + off);
        ph[0] = (unsigned)a | ((unsigned)b << 16);
        ph[1] = (unsigned)c | ((unsigned)d << 16);
        unsigned short la = f2bf(v0.x - bf2f(a)), lb = f2bf(v0.y - bf2f(b));
        unsigned short lc = f2bf(v0.z - bf2f(c)), ld = f2bf(v0.w - bf2f(d));
        unsigned int* pl = (unsigned int*)(sm + 16384 + r * 512 + off);
        pl[0] = (unsigned)la | ((unsigned)lb << 16);
        pl[1] = (unsigned)lc | ((unsigned)ld << 16);
      }
      {
        int r2 = 16 + r;                 // same (row&7) -> same swizzle
        unsigned short a = f2bf(v1.x), b = f2bf(v1.y), c = f2bf(v1.z), d = f2bf(v1.w);
        unsigned int* ph = (unsigned int*)(sm + r2 * 512 + off);
        ph[0] = (unsigned)a | ((unsigned)b << 16);
        ph[1] = (unsigned)c | ((unsigned)d << 16);
        unsigned short la = f2bf(v1.x - bf2f(a)), lb = f2bf(v1.y - bf2f(b));
        unsigned short lc = f2bf(v1.z - bf2f(c)), ld = f2bf(v1.w - bf2f(d));
        unsigned int* pl = (unsigned int*)(sm + 16384 + r2 * 512 + off);
        pl[0] = (unsigned)la | ((unsigned)lb << 16);
        pl[1] = (unsigned)lc | ((unsigned)ld << 16);
      }
    }
  }
  __syncthreads();

  // ---- two projection layers: out = act(X @ W^T + b) ----
  for (int layer = 0; layer < 2; ++layer) {
    const f32x4 vzero = {0.f, 0.f, 0.f, 0.f};
    f32x4 acc[2][4];
    #pragma unroll
    for (int i = 0; i < 2; ++i)
      #pragma unroll
      for (int j = 0; j < 4; ++j) acc[i][j] = vzero;

    const float* bl_ = layer ? g_b2 : g_b1;
    for (int ks = 0; ks < 8; ++ks) {
      const int koff = (ks << 6) + (fg << 4);
      const int aoff = koff ^ ((fr & 7) << 4);
      s16x8 ah0 = *(const s16x8*)(sm +          fr * 512       + aoff);
      s16x8 ah1 = *(const s16x8*)(sm +         (16 + fr) * 512 + aoff);
      s16x8 al0 = *(const s16x8*)(sm + 16384 +  fr * 512       + aoff);
      s16x8 al1 = *(const s16x8*)(sm + 16384 + (16 + fr) * 512 + aoff);
      const size_t fb = ((((size_t)layer * 8 + ks) * 16 + (wid << 2)) * 64 + lane) * 8;
      #pragma unroll
      for (int nt = 0; nt < 4; ++nt) {
        s16x8 bh  = *(const s16x8*)(wh + fb + (size_t)nt * 512);
        s16x8 blo = *(const s16x8*)(wl + fb + (size_t)nt * 512);
        // 3-product split: hi*hi + hi*lo + lo*hi (lo*lo dropped, ~2^-18)
        acc[0][nt] = __builtin_amdgcn_mfma_f32_16x16x32_bf16(ah0, bh,  acc[0][nt], 0, 0, 0);
        acc[1][nt] = __builtin_amdgcn_mfma_f32_16x16x32_bf16(ah1, bh,  acc[1][nt], 0, 0, 0);
        acc[0][nt] = __builtin_amdgcn_mfma_f32_16x16x32_bf16(ah0, blo, acc[0][nt], 0, 0, 0);
        acc[1][nt] = __builtin_amdgcn_mfma_f32_16x16x32_bf16(ah1, blo, acc[1][nt], 0, 0, 0);
        acc[0][nt] = __builtin_amdgcn_mfma_f32_16x16x32_bf16(al0, bh,  acc[0][nt], 0, 0, 0);
        acc[1][nt] = __builtin_amdgcn_mfma_f32_16x16x32_bf16(al1, bh,  acc[1][nt], 0, 0, 0);
      }
    }
    __syncthreads();   // all x reads done before overwrite

    // D frag lane map (verified): row=(lane>>4)*4+reg (+16*mt), col=lane&15 (+16*nt+64*wid)
    float bv[4];
    #pragma unroll
    for (int nt = 0; nt < 4; ++nt) bv[nt] = bl_[(wid << 6) + (nt << 4) + fr];
    if (layer == 0) {
      #pragma unroll
      for (int mt = 0; mt < 2; ++mt) {
        #pragma unroll
        for (int nt = 0; nt < 4; ++nt) {
          #pragma unroll
          for (int j = 0; j < 4; ++j) {
            float h = fmaxf(acc[mt][nt][j] + bv[nt], 0.f);
            int row = (mt << 4) + (fg << 2) + j;
            int col = (wid << 6) + (nt << 4) + fr;
            int off = ((col << 1) ^ ((row & 7) << 4));
            unsigned short hh = f2bf(h);
            unsigned short hl = f2bf(h - bf2f(hh));
            *(unsigned short*)(sm +         row * 512 + off) = hh;
            *(unsigned short*)(sm + 16384 + row * 512 + off) = hl;
          }
        }
      }
      __syncthreads();
    } else {
      float* p = (float*)sm;          // f32 [32][260]
      #pragma unroll
      for (int mt = 0; mt < 2; ++mt) {
        #pragma unroll
        for (int nt = 0; nt < 4; ++nt) {
          #pragma unroll
          for (int j = 0; j < 4; ++j) {
            int row = (mt << 4) + (fg << 2) + j;
            int col = (wid << 6) + (nt << 4) + fr;
            p[row * 260 + col] = acc[mt][nt][j] + bv[nt];
          }
        }
      }
      __syncthreads();
    }
  }

  // ---- C[k][m] = ||pq_k - pr_m|| (clamp d2 at 1e-6 like reference) ----
  const int tk = tid >> 4, tm = tid & 15;
  float C_reg;
  {
    const float* pq_ = (const float*)sm + tk * 260;
    const float* pr_ = (const float*)sm + (16 + tm) * 260;
    float d2 = 0.f;
    #pragma unroll 8
    for (int d = 0; d < 256; d += 4) {
      float4 a = *(const float4*)(pq_ + d);
      float4 c = *(const float4*)(pr_ + d);
      float e0 = a.x - c.x, e1 = a.y - c.y, e2 = a.z - c.z, e3 = a.w - c.w;
      d2 += e0 * e0 + e1 * e1 + e2 * e2 + e3 * e3;
    }
    C_reg = sqrtf(fmaxf(d2, 1e-6f));
  }
  g_out[OFF_C + (size_t)bId * 256 + tid] = C_reg;
}

// ---------------------------------------------------------------------------
// fgw_sink: one block per batch; reads C from g_out, runs 5 FGW outer
// iterations x 10 sinkhorn; writes T, cost, sigmoid(-cost).
__global__ __launch_bounds__(256, 6)
void fgw_sink(const float* __restrict__ g_mq, const float* __restrict__ g_mr,
              const float* __restrict__ g_cq, const float* __restrict__ g_cr,
              const float* __restrict__ g_leps, float* __restrict__ g_out)
{
  __shared__ float sk[2368];
  float* Sq   = sk;        float* Sr   = sk + 272;
  float* Sq2  = sk + 544;  float* Sr2  = sk + 816;
  float* Tlm  = sk + 1088; float* Ttm  = sk + 1360;
  float* Mm   = sk + 1632; float* St   = sk + 1904;
  float* trow = sk + 2176; float* tcol = sk + 2192; float* vl = sk + 2208;
  float* mul_ = sk + 2224; float* nul_ = sk + 2240;
  float* lmu  = sk + 2256; float* lnu  = sk + 2272;
  float* cqx  = sk + 2288; float* cqy  = sk + 2304;
  float* crx  = sk + 2320; float* cry  = sk + 2336;
  float* red  = sk + 2352;

  const int bId  = blockIdx.x;
  const int tid  = threadIdx.x;
  const int lane = tid & 63, wid = tid >> 6;

  if (tid < 32) {          // centroids + masks -> mu/nu, log mu/nu
    int i = tid & 15;
    const float* cc = (tid < 16 ? g_cq : g_cr) + (size_t)bId * 32 + (i << 1);
    float cx = cc[0], cy = cc[1];
    float mv = (tid < 16 ? g_mq : g_mr)[(size_t)bId * 16 + i];
    float s  = rsum16(mv);
    float muv = mv / (s + 1e-8f);
    float lg  = __logf(fmaxf(muv, 1e-8f));
    if (tid < 16) { cqx[i] = cx; cqy[i] = cy; mul_[i] = muv; lmu[i] = lg; }
    else          { crx[i] = cx; cry[i] = cy; nul_[i] = muv; lnu[i] = lg; }
  }
  const int tk = tid >> 4, tm = tid & 15;
  float C_reg = g_out[OFF_C + (size_t)bId * 256 + tid];
  __syncthreads();

  {  // Sq/Sr centroid distance matrices (clamp BEFORE sqrt, like reference)
    float dx = cqx[tk] - cqx[tm], dy = cqy[tk] - cqy[tm];
    float s1 = sqrtf(fmaxf(dx * dx + dy * dy, 1e-6f));
    Sq[tk * 17 + tm] = s1;  Sq2[tk * 17 + tm] = s1 * s1;
    float ex = crx[tk] - crx[tm], ey = cry[tk] - cry[tm];
    float s2 = sqrtf(fmaxf(ex * ex + ey * ey, 1e-6f));
    Sr[tk * 17 + tm] = s2;  Sr2[tk * 17 + tm] = s2 * s2;
  }
  float eps = __expf(g_leps[0]);
  eps = fminf(fmaxf(eps, 0.01f), 0.5f);
  const float inv_eps = 1.0f / eps;
  const float rho = 0.1f / (0.1f + eps);
  float T_reg = mul_[tk] * nul_[tm];
  Tlm[tk * 17 + tm] = T_reg;  Ttm[tm * 17 + tk] = T_reg;
  const float lmu_k = lmu[tk], lnu_k = lnu[tk];
  __syncthreads();

  // ---- 5 outer FGW iterations, 10 sinkhorn each ----
  float Cfgw = 0.f, logK = 0.f, u_reg = 0.f, v_reg = 0.f;
  for (int it = 0; it < 5; ++it) {
    float tr = rsum16(T_reg);                 // row sums of T
    float tc = rsum16(Ttm[tk * 17 + tm]);     // col sums of T
    if (tm == 0) { trow[tk] = tr; tcol[tk] = tc; }
    __syncthreads();
    float t1 = rsum16(Sq2[tk * 17 + tm] * trow[tm]);
    float t2 = 0.f;
    #pragma unroll
    for (int l = 0; l < 16; ++l) t2 += tcol[l] * Sr2[l * 17 + tm];
    float m1 = 0.f;
    #pragma unroll
    for (int l = 0; l < 16; ++l) m1 += Tlm[tk * 17 + l] * Sr[l * 17 + tm];
    Mm[tk * 17 + tm] = m1;
    __syncthreads();
    float t3 = 0.f;
    #pragma unroll
    for (int l = 0; l < 16; ++l) t3 += Sq[tk * 17 + l] * Mm[l * 17 + tm];
    Cfgw = 0.5f * C_reg + 0.5f * (t1 + t2 - 2.0f * t3);
    logK = -Cfgw * inv_eps;
    u_reg = 0.f; v_reg = 0.f;
    for (int s = 0; s < 10; ++s) {
      // log_u = rho*(log_mu - LSE_m(logK + v))   [within 16-lane group]
      float x  = logK + v_reg;
      float mx = rmax16(x);
      float lse = mx + __logf(rsum16(__expf(x - mx)));
      u_reg = rho * (lmu_k - lse);
      // log_v = rho*(log_nu - LSE_k(logK + u))   [via LDS transpose]
      St[tm * 17 + tk] = logK + u_reg;
      __syncthreads();
      float y  = St[tk * 17 + tm];
      float my = rmax16(y);
      float lse2 = my + __logf(rsum16(__expf(y - my)));
      if (tm == 0) vl[tk] = rho * (lnu_k - lse2);
      __syncthreads();
      v_reg = vl[tm];
    }
    T_reg = __expf(u_reg + logK + v_reg);
    Tlm[tk * 17 + tm] = T_reg;  Ttm[tm * 17 + tk] = T_reg;
    __syncthreads();
  }

  // ---- outputs ----
  float cp = T_reg * Cfgw;
  cp += __shfl_xor(cp, 1);  cp += __shfl_xor(cp, 2);  cp += __shfl_xor(cp, 4);
  cp += __shfl_xor(cp, 8);  cp += __shfl_xor(cp, 16); cp += __shfl_xor(cp, 32);
  if (lane == 0) red[wid] = cp;
  __syncthreads();
  g_out[OFF_T + (size_t)bId * 256 + tid] = T_reg;
  if (tid == 0) {
    float cost = red[0] + red[1] + red[2] + red[3];
    g_out[bId] = 1.0f / (1.0f + __expf(cost));   // sigmoid(-cost)
    g_out[OFF_CST + bId] = cost;
  }
}

extern "C" void kernel_launch(void* const* d_in, const int* in_sizes, int n_in,
                              void* d_out, int out_size, void* d_ws, size_t ws_size,
                              hipStream_t stream) {
  (void)in_sizes; (void)n_in; (void)out_size; (void)ws_size;
  unsigned int*   wh32 = (unsigned int*)d_ws;
  unsigned int*   wl32 = wh32 + 65536;                 // 262,144 B each
  unsigned short* wh   = (unsigned short*)wh32;
  unsigned short* wl   = (unsigned short*)wl32;

  prep_w<<<dim3(64), dim3(256), 0, stream>>>(
      (const float*)d_in[6], (const float*)d_in[8], wh32, wl32);
  fgw_proj<<<dim3(8192), dim3(256), 0, stream>>>(
      (const float*)d_in[0], (const float*)d_in[1], wh, wl,
      (const float*)d_in[7], (const float*)d_in[9], (float*)d_out);
  fgw_sink<<<dim3(8192), dim3(256), 0, stream>>>(
      (const float*)d_in[2], (const float*)d_in[3],
      (const float*)d_in[4], (const float*)d_in[5],
      (const float*)d_in[10], (float*)d_out);
}

// Round 3
// 354.133 us; speedup vs baseline: 3.3312x; 1.7739x over previous
//
#include <hip/hip_runtime.h>

// FusedGromovWasserstein — 3 kernels:
//  prep_w:   W1,W2 f32 -> pre-split bf16 hi/lo MFMA B-fragments in d_ws
//  fgw_proj: 2 batches/block; 2-layer MLP via split-bf16 MFMA; C via
//            G=pq@pr^T MFMA + norms (C = sqrt(nq+nr-2G), like reference)
//  fgw_sink: 1 wave/batch, barrier-free; DPP row-reduces, swizzle/shfl
//            col-reduces; 5 outer x 10 sinkhorn fully in registers.
// Outputs flat: [sigmoid(-cost) 8192][T 8192*256][C 8192*256][cost 8192].

#define OFF_T   8192
#define OFF_C   2105344
#define OFF_CST 4202496

typedef float  f32x4 __attribute__((ext_vector_type(4)));
typedef short  s16x8 __attribute__((ext_vector_type(8)));

__device__ __forceinline__ unsigned short f2bf(float f) {
  unsigned int u = __float_as_uint(f);
  u += 0x7FFFu + ((u >> 16) & 1u);          // round-to-nearest-even
  return (unsigned short)(u >> 16);
}
__device__ __forceinline__ float bf2f(unsigned short h) {
  return __uint_as_float(((unsigned int)h) << 16);
}

// ---- cross-lane reduction helpers (DPP = pure VALU, no LDS traffic) ----
template <int CTRL>
__device__ __forceinline__ float dpp_add(float x) {
  return x + __int_as_float(__builtin_amdgcn_update_dpp(
      0, __float_as_int(x), CTRL, 0xf, 0xf, true));
}
template <int CTRL>
__device__ __forceinline__ float dpp_max(float x) {
  return fmaxf(x, __int_as_float(__builtin_amdgcn_update_dpp(
      0, __float_as_int(x), CTRL, 0xf, 0xf, true)));
}
// all-reduce within each 16-lane row: xor1, xor2 (quad_perm), ror4, ror8
__device__ __forceinline__ float row16_sum(float x) {
  x = dpp_add<0xB1>(x);  x = dpp_add<0x4E>(x);
  x = dpp_add<0x124>(x); x = dpp_add<0x128>(x);
  return x;
}
__device__ __forceinline__ float row16_max(float x) {
  x = dpp_max<0xB1>(x);  x = dpp_max<0x4E>(x);
  x = dpp_max<0x124>(x); x = dpp_max<0x128>(x);
  return x;
}
__device__ __forceinline__ float xor16_add(float x) {
  return x + __int_as_float(__builtin_amdgcn_ds_swizzle(__float_as_int(x), 0x401F));
}
__device__ __forceinline__ float xor16_max(float x) {
  return fmaxf(x, __int_as_float(__builtin_amdgcn_ds_swizzle(__float_as_int(x), 0x401F)));
}
__device__ __forceinline__ float xor32_add(float x) { return x + __shfl_xor(x, 32); }
__device__ __forceinline__ float xor32_max(float x) { return fmaxf(x, __shfl_xor(x, 32)); }

// ---------------------------------------------------------------------------
// prep_w: 16384 fragments (2 layers x 8 ksteps x 16 colgroups x 64 lanes).
__global__ __launch_bounds__(256, 1)
void prep_w(const float* __restrict__ W1, const float* __restrict__ W2,
            unsigned int* __restrict__ wh, unsigned int* __restrict__ wl)
{
  const int fid  = blockIdx.x * 256 + threadIdx.x;   // 0..16383
  const int l    = fid >> 13;
  const int s    = (fid >> 10) & 7;
  const int cg   = (fid >> 6) & 15;
  const int lane = fid & 63;
  const int fr   = lane & 15, fg = lane >> 4;
  const int col  = cg * 16 + fr;
  const float* W = l ? W2 : W1;
  const float* src = W + ((size_t)col << 8) + (s << 5) + (fg << 3);
  float4 a = *(const float4*)src;
  float4 b = *(const float4*)(src + 4);
  float f[8] = {a.x, a.y, a.z, a.w, b.x, b.y, b.z, b.w};
  unsigned int uh[4], ul[4];
  #pragma unroll
  for (int i = 0; i < 4; ++i) {
    unsigned short h0 = f2bf(f[2*i]),            h1 = f2bf(f[2*i+1]);
    unsigned short l0 = f2bf(f[2*i]   - bf2f(h0));
    unsigned short l1 = f2bf(f[2*i+1] - bf2f(h1));
    uh[i] = (unsigned)h0 | ((unsigned)h1 << 16);
    ul[i] = (unsigned)l0 | ((unsigned)l1 << 16);
  }
  uint4 vh = {uh[0], uh[1], uh[2], uh[3]};
  uint4 vl = {ul[0], ul[1], ul[2], ul[3]};
  ((uint4*)wh)[fid] = vh;
  ((uint4*)wl)[fid] = vl;
}

// ---------------------------------------------------------------------------
// fgw_proj: 2 batches per block. Per-batch x-tile: hi [0,16K) lo [16K,32K),
// rows 0-15 q / 16-31 r, row stride 512B, XOR swizzle ((row&7)<<4).
__global__ __launch_bounds__(256, 2)
void fgw_proj(const float* __restrict__ g_q,  const float* __restrict__ g_r,
              const unsigned short* __restrict__ wh,
              const unsigned short* __restrict__ wl,
              const float* __restrict__ g_b1, const float* __restrict__ g_b2,
              float* __restrict__ g_out)
{
  __shared__ __align__(16) float smemf[16640];   // 66,560 B
  char* sm = (char*)smemf;
  const int bId0 = blockIdx.x * 2;
  const int tid  = threadIdx.x;
  const int lane = tid & 63, wid = tid >> 6;
  const int fr   = lane & 15, fg = lane >> 4;

  // ---- stage 2 batches as hi/lo bf16 ----
  #pragma unroll
  for (int j = 0; j < 8; ++j) {
    int idx = (j << 8) + tid;          // 0..2047
    int bb  = idx >> 10;
    int t   = idx & 1023;
    int r   = t >> 6;
    int sg  = t & 63;
    int off = ((sg << 3) ^ ((r & 7) << 4));
    char* xb = sm + bb * 32768;
    const float* xq = g_q + (size_t)(bId0 + bb) * 4096 + (r << 8) + (sg << 2);
    const float* xr = g_r + (size_t)(bId0 + bb) * 4096 + (r << 8) + (sg << 2);
    float4 v0 = *(const float4*)xq;
    float4 v1 = *(const float4*)xr;
    {
      unsigned short ha = f2bf(v0.x), hb = f2bf(v0.y), hc = f2bf(v0.z), hd = f2bf(v0.w);
      unsigned int* ph = (unsigned int*)(xb + r * 512 + off);
      ph[0] = (unsigned)ha | ((unsigned)hb << 16);
      ph[1] = (unsigned)hc | ((unsigned)hd << 16);
      unsigned short la = f2bf(v0.x - bf2f(ha)), lb = f2bf(v0.y - bf2f(hb));
      unsigned short lc = f2bf(v0.z - bf2f(hc)), ld = f2bf(v0.w - bf2f(hd));
      unsigned int* pl = (unsigned int*)(xb + 16384 + r * 512 + off);
      pl[0] = (unsigned)la | ((unsigned)lb << 16);
      pl[1] = (unsigned)lc | ((unsigned)ld << 16);
    }
    {
      int r2 = 16 + r;                 // same (row&7) -> same swizzle
      unsigned short ha = f2bf(v1.x), hb = f2bf(v1.y), hc = f2bf(v1.z), hd = f2bf(v1.w);
      unsigned int* ph = (unsigned int*)(xb + r2 * 512 + off);
      ph[0] = (unsigned)ha | ((unsigned)hb << 16);
      ph[1] = (unsigned)hc | ((unsigned)hd << 16);
      unsigned short la = f2bf(v1.x - bf2f(ha)), lb = f2bf(v1.y - bf2f(hb));
      unsigned short lc = f2bf(v1.z - bf2f(hc)), ld = f2bf(v1.w - bf2f(hd));
      unsigned int* pl = (unsigned int*)(xb + 16384 + r2 * 512 + off);
      pl[0] = (unsigned)la | ((unsigned)lb << 16);
      pl[1] = (unsigned)lc | ((unsigned)ld << 16);
    }
  }
  __syncthreads();

  // ---- two layers: out = act(X @ W^T + b), X is 64 rows (2 batches) ----
  for (int layer = 0; layer < 2; ++layer) {
    const f32x4 vzero = {0.f, 0.f, 0.f, 0.f};
    f32x4 acc[2][2][4];
    #pragma unroll
    for (int bb = 0; bb < 2; ++bb)
      #pragma unroll
      for (int i = 0; i < 2; ++i)
        #pragma unroll
        for (int j = 0; j < 4; ++j) acc[bb][i][j] = vzero;

    const float* bl_ = layer ? g_b2 : g_b1;
    for (int ks = 0; ks < 8; ++ks) {
      const int koff = (ks << 6) + (fg << 4);
      const int aoff = koff ^ ((fr & 7) << 4);
      s16x8 ah[2][2], al[2][2];
      #pragma unroll
      for (int bb = 0; bb < 2; ++bb) {
        char* xb = sm + bb * 32768;
        ah[bb][0] = *(const s16x8*)(xb +          fr * 512       + aoff);
        ah[bb][1] = *(const s16x8*)(xb +         (16 + fr) * 512 + aoff);
        al[bb][0] = *(const s16x8*)(xb + 16384 +  fr * 512       + aoff);
        al[bb][1] = *(const s16x8*)(xb + 16384 + (16 + fr) * 512 + aoff);
      }
      const size_t fb = ((((size_t)layer * 8 + ks) * 16 + (wid << 2)) * 64 + lane) * 8;
      #pragma unroll
      for (int nt = 0; nt < 4; ++nt) {
        s16x8 bh  = *(const s16x8*)(wh + fb + (size_t)nt * 512);
        s16x8 blo = *(const s16x8*)(wl + fb + (size_t)nt * 512);
        #pragma unroll
        for (int bb = 0; bb < 2; ++bb) {
          acc[bb][0][nt] = __builtin_amdgcn_mfma_f32_16x16x32_bf16(ah[bb][0], bh,  acc[bb][0][nt], 0, 0, 0);
          acc[bb][1][nt] = __builtin_amdgcn_mfma_f32_16x16x32_bf16(ah[bb][1], bh,  acc[bb][1][nt], 0, 0, 0);
          acc[bb][0][nt] = __builtin_amdgcn_mfma_f32_16x16x32_bf16(ah[bb][0], blo, acc[bb][0][nt], 0, 0, 0);
          acc[bb][1][nt] = __builtin_amdgcn_mfma_f32_16x16x32_bf16(ah[bb][1], blo, acc[bb][1][nt], 0, 0, 0);
          acc[bb][0][nt] = __builtin_amdgcn_mfma_f32_16x16x32_bf16(al[bb][0], bh,  acc[bb][0][nt], 0, 0, 0);
          acc[bb][1][nt] = __builtin_amdgcn_mfma_f32_16x16x32_bf16(al[bb][1], bh,  acc[bb][1][nt], 0, 0, 0);
        }
      }
    }
    __syncthreads();   // all x reads done before in-place overwrite

    float bv[4];
    #pragma unroll
    for (int nt = 0; nt < 4; ++nt) bv[nt] = bl_[(wid << 6) + (nt << 4) + fr];

    if (layer == 0) {
      #pragma unroll
      for (int bb = 0; bb < 2; ++bb) {
        char* xb = sm + bb * 32768;
        #pragma unroll
        for (int mt = 0; mt < 2; ++mt)
          #pragma unroll
          for (int nt = 0; nt < 4; ++nt)
            #pragma unroll
            for (int j = 0; j < 4; ++j) {
              float h = fmaxf(acc[bb][mt][nt][j] + bv[nt], 0.f);
              int row = (mt << 4) + (fg << 2) + j;
              int col = (wid << 6) + (nt << 4) + fr;
              int off = ((col << 1) ^ ((row & 7) << 4));
              unsigned short hh = f2bf(h);
              unsigned short hl = f2bf(h - bf2f(hh));
              *(unsigned short*)(xb +         row * 512 + off) = hh;
              *(unsigned short*)(xb + 16384 + row * 512 + off) = hl;
            }
      }
      __syncthreads();
    } else {
      // layer 2: norms (per-wave partials) + write p as hi/lo bf16 in place
      float* normL = smemf + 16384;    // [2][4][32] floats at byte 65536
      #pragma unroll
      for (int bb = 0; bb < 2; ++bb) {
        char* xb = sm + bb * 32768;
        #pragma unroll
        for (int mt = 0; mt < 2; ++mt)
          #pragma unroll
          for (int j = 0; j < 4; ++j) {
            float pv[4];
            #pragma unroll
            for (int nt = 0; nt < 4; ++nt) pv[nt] = acc[bb][mt][nt][j] + bv[nt];
            float s = pv[0]*pv[0] + pv[1]*pv[1] + pv[2]*pv[2] + pv[3]*pv[3];
            s = row16_sum(s);          // sum over fr (16 cols per nt)
            int row = (mt << 4) + (fg << 2) + j;
            if (fr == 0) normL[(bb * 4 + wid) * 32 + row] = s;
            #pragma unroll
            for (int nt = 0; nt < 4; ++nt) {
              int col = (wid << 6) + (nt << 4) + fr;
              int off = ((col << 1) ^ ((row & 7) << 4));
              unsigned short hh = f2bf(pv[nt]);
              unsigned short hl = f2bf(pv[nt] - bf2f(hh));
              *(unsigned short*)(xb +         row * 512 + off) = hh;
              *(unsigned short*)(xb + 16384 + row * 512 + off) = hl;
            }
          }
      }
      __syncthreads();
    }
  }

  // ---- G = pq @ pr^T per batch via split MFMA (each wave: 2 ksteps) ----
  const f32x4 vz = {0.f, 0.f, 0.f, 0.f};
  f32x4 accG[2] = {vz, vz};
  #pragma unroll
  for (int bb = 0; bb < 2; ++bb) {
    char* xb = sm + bb * 32768;
    #pragma unroll
    for (int kk = 0; kk < 2; ++kk) {
      int ks   = wid * 2 + kk;
      int koff = (ks << 6) + (fg << 4);
      int aoff = koff ^ ((fr & 7) << 4);
      s16x8 aqh = *(const s16x8*)(xb +          fr * 512       + aoff);
      s16x8 aql = *(const s16x8*)(xb + 16384 +  fr * 512       + aoff);
      s16x8 brh = *(const s16x8*)(xb +         (16 + fr) * 512 + aoff);
      s16x8 brl = *(const s16x8*)(xb + 16384 + (16 + fr) * 512 + aoff);
      accG[bb] = __builtin_amdgcn_mfma_f32_16x16x32_bf16(aqh, brh, accG[bb], 0, 0, 0);
      accG[bb] = __builtin_amdgcn_mfma_f32_16x16x32_bf16(aqh, brl, accG[bb], 0, 0, 0);
      accG[bb] = __builtin_amdgcn_mfma_f32_16x16x32_bf16(aql, brh, accG[bb], 0, 0, 0);
    }
  }
  __syncthreads();                       // all G-input reads complete
  float* Gp = smemf;                     // [2][4][256] overlays bytes [0,8192)
  #pragma unroll
  for (int bb = 0; bb < 2; ++bb)
    #pragma unroll
    for (int j = 0; j < 4; ++j)
      Gp[(bb * 4 + wid) * 256 + ((fg << 2) + j) * 16 + fr] = accG[bb][j];
  __syncthreads();

  // ---- C = sqrt(max(nq + nr - 2G, 1e-6)) ----
  const int tk = tid >> 4, tm = tid & 15;
  const float* normL = smemf + 16384;
  #pragma unroll
  for (int bb = 0; bb < 2; ++bb) {
    float Gv = Gp[(bb*4+0)*256 + tk*16 + tm] + Gp[(bb*4+1)*256 + tk*16 + tm]
             + Gp[(bb*4+2)*256 + tk*16 + tm] + Gp[(bb*4+3)*256 + tk*16 + tm];
    float nq = normL[(bb*4+0)*32 + tk] + normL[(bb*4+1)*32 + tk]
             + normL[(bb*4+2)*32 + tk] + normL[(bb*4+3)*32 + tk];
    float nr = normL[(bb*4+0)*32 + 16 + tm] + normL[(bb*4+1)*32 + 16 + tm]
             + normL[(bb*4+2)*32 + 16 + tm] + normL[(bb*4+3)*32 + 16 + tm];
    float d2 = nq + nr - 2.0f * Gv;
    g_out[OFF_C + (size_t)(bId0 + bb) * 256 + tid] = sqrtf(fmaxf(d2, 1e-6f));
  }
}

// ---------------------------------------------------------------------------
// fgw_sink: 1 wave per batch, 4 waves/block, zero barriers.
// Lane layout: m = lane&15 (column), k_j = 4*(lane>>4)+j (4 rows per lane).
// Per-batch LDS region (floats, stride 20 rows => 16B-aligned b128):
//   Sq 0, Sr 320, Tt 640, M1 960, lmu 1280, mu 1296, cqx 1312, cqy 1328,
//   crx 1344, cry 1360, trow 1376, tcol 1392   (total 1408)
__global__ __launch_bounds__(256, 4)
void fgw_sink(const float* __restrict__ g_mq, const float* __restrict__ g_mr,
              const float* __restrict__ g_cq, const float* __restrict__ g_cr,
              const float* __restrict__ g_leps, float* __restrict__ g_out)
{
  __shared__ __align__(16) float sk[4 * 1408];
  const int tid  = threadIdx.x, lane = tid & 63, w = tid >> 6;
  const int batch = blockIdx.x * 4 + w;
  const int m = lane & 15, g = lane >> 4;
  float* L     = sk + w * 1408;
  float* SqL   = L;        float* SrL   = L + 320;
  float* TtL   = L + 640;  float* M1L   = L + 960;
  float* lmuL  = L + 1280; float* muL   = L + 1296;
  float* cqxL  = L + 1312; float* cqyL  = L + 1328;
  float* crxL  = L + 1344; float* cryL  = L + 1360;
  float* trowL = L + 1376; float* tcolL = L + 1392;

  // ---- masks -> mu/nu (per-lane index m), redistribute to k_j via LDS ----
  float mqv = g_mq[(size_t)batch * 16 + m];
  float mrv = g_mr[(size_t)batch * 16 + m];
  float mu_m = mqv / (row16_sum(mqv) + 1e-8f);
  float nu_m = mrv / (row16_sum(mrv) + 1e-8f);
  float lmu_m = __logf(fmaxf(mu_m, 1e-8f));
  float lnu_m = __logf(fmaxf(nu_m, 1e-8f));
  float cqx_m = g_cq[(size_t)batch * 32 + 2 * m];
  float cqy_m = g_cq[(size_t)batch * 32 + 2 * m + 1];
  float crx_m = g_cr[(size_t)batch * 32 + 2 * m];
  float cry_m = g_cr[(size_t)batch * 32 + 2 * m + 1];
  if (g == 0) {
    lmuL[m] = lmu_m;  muL[m] = mu_m;
    cqxL[m] = cqx_m;  cqyL[m] = cqy_m;
    crxL[m] = crx_m;  cryL[m] = cry_m;
  }
  f32x4 lmu_j = *(const f32x4*)(lmuL + 4 * g);
  f32x4 mu_j  = *(const f32x4*)(muL  + 4 * g);
  f32x4 cqxj  = *(const f32x4*)(cqxL + 4 * g);
  f32x4 cqyj  = *(const f32x4*)(cqyL + 4 * g);
  f32x4 crxj  = *(const f32x4*)(crxL + 4 * g);
  f32x4 cryj  = *(const f32x4*)(cryL + 4 * g);

  // ---- Sq/Sr (rows k_j, col m); Sq2/Sr2 kept in registers ----
  float Sq2r[4], Sr2r[4];
  #pragma unroll
  for (int j = 0; j < 4; ++j) {
    float dx = cqxj[j] - cqx_m, dy = cqyj[j] - cqy_m;
    float d2 = fmaxf(dx * dx + dy * dy, 1e-6f);
    SqL[(4 * g + j) * 20 + m] = sqrtf(d2);
    Sq2r[j] = d2;
    float ex = crxj[j] - crx_m, ey = cryj[j] - cry_m;
    float e2 = fmaxf(ex * ex + ey * ey, 1e-6f);
    SrL[(4 * g + j) * 20 + m] = sqrtf(e2);
    Sr2r[j] = e2;
  }

  // ---- C, eps, T init ----
  float C_[4];
  const float* Cp = g_out + OFF_C + (size_t)batch * 256;
  #pragma unroll
  for (int j = 0; j < 4; ++j) C_[j] = Cp[(4 * g + j) * 16 + m];
  float eps = fminf(fmaxf(__expf(g_leps[0]), 0.01f), 0.5f);
  const float inv_eps = 1.0f / eps;
  const float rho = 0.1f / (0.1f + eps);
  float rlmu[4];
  #pragma unroll
  for (int j = 0; j < 4; ++j) rlmu[j] = rho * lmu_j[j];
  const float rlnu = rho * lnu_m;
  float T_[4];
  #pragma unroll
  for (int j = 0; j < 4; ++j) T_[j] = mu_j[j] * nu_m;

  float Cf[4], logK[4], KM[4], Mx[4], u_[4], v = 0.f;

  // ---- 5 outer FGW iterations ----
  for (int it = 0; it < 5; ++it) {
    // row sums trow[k_j] (over m: DPP) and col sums tcol[m] (over k)
    float trow_j[4];
    #pragma unroll
    for (int j = 0; j < 4; ++j) trow_j[j] = row16_sum(T_[j]);
    float tc = xor32_add(xor16_add(T_[0] + T_[1] + T_[2] + T_[3]));
    if (m == 0) { f32x4 tv = {trow_j[0], trow_j[1], trow_j[2], trow_j[3]};
                  *(f32x4*)(trowL + 4 * g) = tv; }
    if (g == 0) tcolL[m] = tc;
    // Tt[m][k] = T[k][m]
    { f32x4 tv = {T_[0], T_[1], T_[2], T_[3]};
      *(f32x4*)(TtL + m * 20 + 4 * g) = tv; }

    // t1[k_j] = sum_m Sq2[k_j,m]*trow[m]  (DPP over m)
    float trow_m = trowL[m];
    float t1_[4];
    #pragma unroll
    for (int j = 0; j < 4; ++j) t1_[j] = row16_sum(Sq2r[j] * trow_m);
    // t2[m] = sum_l tcol[l]*Sr2[l,m]  (partial over lane's k_j, xor over g)
    f32x4 tcv = *(const f32x4*)(tcolL + 4 * g);
    float p2 = tcv[0] * Sr2r[0] + tcv[1] * Sr2r[1] + tcv[2] * Sr2r[2] + tcv[3] * Sr2r[3];
    float t2_ = xor32_add(xor16_add(p2));

    // M1[k_j,m] = sum_l T[k_j,l]*Sr[l,m]
    float M1r[4] = {0.f, 0.f, 0.f, 0.f};
    #pragma unroll
    for (int l = 0; l < 16; ++l) {
      f32x4 t4 = *(const f32x4*)(TtL + l * 20 + 4 * g);
      float srv = SrL[l * 20 + m];
      M1r[0] += t4[0] * srv; M1r[1] += t4[1] * srv;
      M1r[2] += t4[2] * srv; M1r[3] += t4[3] * srv;
    }
    #pragma unroll
    for (int j = 0; j < 4; ++j) M1L[(4 * g + j) * 20 + m] = M1r[j];
    // t3[k_j,m] = sum_l Sq[l,k_j]*M1[l,m]   (Sq symmetric)
    float t3_[4] = {0.f, 0.f, 0.f, 0.f};
    #pragma unroll
    for (int l = 0; l < 16; ++l) {
      f32x4 sq4 = *(const f32x4*)(SqL + l * 20 + 4 * g);
      float m1v = M1L[l * 20 + m];
      t3_[0] += sq4[0] * m1v; t3_[1] += sq4[1] * m1v;
      t3_[2] += sq4[2] * m1v; t3_[3] += sq4[3] * m1v;
    }

    #pragma unroll
    for (int j = 0; j < 4; ++j) {
      float lgw = t1_[j] + t2_ - 2.0f * t3_[j];
      Cf[j]   = 0.5f * C_[j] + 0.5f * lgw;
      logK[j] = -inv_eps * Cf[j];
      Mx[j]   = row16_max(logK[j]);     // static row shift (underflow-safe)
      KM[j]   = logK[j] - Mx[j];
    }

    // ---- 10 sinkhorn iterations, fully in registers ----
    v = 0.f;
    #pragma unroll 1
    for (int s = 0; s < 10; ++s) {
      // u[k_j] = rho*(lmu - (Mx + log sum_m exp(KM + v)))
      #pragma unroll
      for (int j = 0; j < 4; ++j) {
        float sj = row16_sum(__expf(KM[j] + v));
        u_[j] = rlmu[j] - rho * (Mx[j] + __logf(sj));
      }
      // v[m] = rho*(lnu - logsumexp_k(logK + u))
      float x0 = logK[0] + u_[0], x1 = logK[1] + u_[1];
      float x2 = logK[2] + u_[2], x3 = logK[3] + u_[3];
      float mx = fmaxf(fmaxf(x0, x1), fmaxf(x2, x3));
      mx = xor32_max(xor16_max(mx));
      float ss = __expf(x0 - mx) + __expf(x1 - mx) + __expf(x2 - mx) + __expf(x3 - mx);
      ss = xor32_add(xor16_add(ss));
      v = rlnu - rho * (mx + __logf(ss));
    }
    #pragma unroll
    for (int j = 0; j < 4; ++j) T_[j] = __expf(u_[j] + logK[j] + v);
  }

  // ---- outputs ----
  float cp = T_[0] * Cf[0] + T_[1] * Cf[1] + T_[2] * Cf[2] + T_[3] * Cf[3];
  cp = xor32_add(xor16_add(row16_sum(cp)));
  float* To = g_out + OFF_T + (size_t)batch * 256;
  #pragma unroll
  for (int j = 0; j < 4; ++j) To[(4 * g + j) * 16 + m] = T_[j];
  if (lane == 0) {
    g_out[batch] = 1.0f / (1.0f + __expf(cp));   // sigmoid(-cost)
    g_out[OFF_CST + batch] = cp;
  }
}

extern "C" void kernel_launch(void* const* d_in, const int* in_sizes, int n_in,
                              void* d_out, int out_size, void* d_ws, size_t ws_size,
                              hipStream_t stream) {
  (void)in_sizes; (void)n_in; (void)out_size; (void)ws_size;
  unsigned int*   wh32 = (unsigned int*)d_ws;
  unsigned int*   wl32 = wh32 + 65536;                 // 262,144 B each
  unsigned short* wh   = (unsigned short*)wh32;
  unsigned short* wl   = (unsigned short*)wl32;

  prep_w<<<dim3(64), dim3(256), 0, stream>>>(
      (const float*)d_in[6], (const float*)d_in[8], wh32, wl32);
  fgw_proj<<<dim3(4096), dim3(256), 0, stream>>>(
      (const float*)d_in[0], (const float*)d_in[1], wh, wl,
      (const float*)d_in[7], (const float*)d_in[9], (float*)d_out);
  fgw_sink<<<dim3(2048), dim3(256), 0, stream>>>(
      (const float*)d_in[2], (const float*)d_in[3],
      (const float*)d_in[4], (const float*)d_in[5],
      (const float*)d_in[10], (float*)d_out);
}

// Round 4
// 301.899 us; speedup vs baseline: 3.9075x; 1.1730x over previous
//
#include <hip/hip_runtime.h>

// FusedGromovWasserstein — 3 kernels:
//  prep_w:   W1,W2 f32 -> pre-split bf16 hi/lo MFMA B-fragments in d_ws
//  fgw_proj: 2 batches/block, 512 thr (8 waves, 32 cols each); 2-layer MLP
//            via split-bf16 MFMA; C via G=pq@pr^T MFMA + norms
//  fgw_sink: 1 wave/batch, barrier-free; DPP/swizzle reduces; 5x10 sinkhorn
// Outputs flat: [sigmoid(-cost) 8192][T 8192*256][C 8192*256][cost 8192].

#define OFF_T   8192
#define OFF_C   2105344
#define OFF_CST 4202496

typedef float  f32x4 __attribute__((ext_vector_type(4)));
typedef short  s16x8 __attribute__((ext_vector_type(8)));

__device__ __forceinline__ unsigned short f2bf(float f) {
  unsigned int u = __float_as_uint(f);
  u += 0x7FFFu + ((u >> 16) & 1u);          // round-to-nearest-even
  return (unsigned short)(u >> 16);
}
__device__ __forceinline__ float bf2f(unsigned short h) {
  return __uint_as_float(((unsigned int)h) << 16);
}

// ---- cross-lane reduction helpers (DPP = pure VALU, no LDS traffic) ----
template <int CTRL>
__device__ __forceinline__ float dpp_add(float x) {
  return x + __int_as_float(__builtin_amdgcn_update_dpp(
      0, __float_as_int(x), CTRL, 0xf, 0xf, true));
}
template <int CTRL>
__device__ __forceinline__ float dpp_max(float x) {
  return fmaxf(x, __int_as_float(__builtin_amdgcn_update_dpp(
      0, __float_as_int(x), CTRL, 0xf, 0xf, true)));
}
__device__ __forceinline__ float row16_sum(float x) {
  x = dpp_add<0xB1>(x);  x = dpp_add<0x4E>(x);
  x = dpp_add<0x124>(x); x = dpp_add<0x128>(x);
  return x;
}
__device__ __forceinline__ float row16_max(float x) {
  x = dpp_max<0xB1>(x);  x = dpp_max<0x4E>(x);
  x = dpp_max<0x124>(x); x = dpp_max<0x128>(x);
  return x;
}
__device__ __forceinline__ float xor16_add(float x) {
  return x + __int_as_float(__builtin_amdgcn_ds_swizzle(__float_as_int(x), 0x401F));
}
__device__ __forceinline__ float xor16_max(float x) {
  return fmaxf(x, __int_as_float(__builtin_amdgcn_ds_swizzle(__float_as_int(x), 0x401F)));
}
__device__ __forceinline__ float xor32_add(float x) { return x + __shfl_xor(x, 32); }
__device__ __forceinline__ float xor32_max(float x) { return fmaxf(x, __shfl_xor(x, 32)); }

// ---------------------------------------------------------------------------
// prep_w: 16384 fragments (2 layers x 8 ksteps x 16 colgroups x 64 lanes).
// Fragment holds W[col=cg*16+fr][k = ks*32 + fg*8 + e].
__global__ __launch_bounds__(256, 1)
void prep_w(const float* __restrict__ W1, const float* __restrict__ W2,
            unsigned int* __restrict__ wh, unsigned int* __restrict__ wl)
{
  const int fid  = blockIdx.x * 256 + threadIdx.x;   // 0..16383
  const int l    = fid >> 13;
  const int s    = (fid >> 10) & 7;
  const int cg   = (fid >> 6) & 15;
  const int lane = fid & 63;
  const int fr   = lane & 15, fg = lane >> 4;
  const int col  = cg * 16 + fr;
  const float* W = l ? W2 : W1;
  const float* src = W + ((size_t)col << 8) + (s << 5) + (fg << 3);
  float4 a = *(const float4*)src;
  float4 b = *(const float4*)(src + 4);
  float f[8] = {a.x, a.y, a.z, a.w, b.x, b.y, b.z, b.w};
  unsigned int uh[4], ul[4];
  #pragma unroll
  for (int i = 0; i < 4; ++i) {
    unsigned short h0 = f2bf(f[2*i]),            h1 = f2bf(f[2*i+1]);
    unsigned short l0 = f2bf(f[2*i]   - bf2f(h0));
    unsigned short l1 = f2bf(f[2*i+1] - bf2f(h1));
    uh[i] = (unsigned)h0 | ((unsigned)h1 << 16);
    ul[i] = (unsigned)l0 | ((unsigned)l1 << 16);
  }
  uint4 vh = {uh[0], uh[1], uh[2], uh[3]};
  uint4 vl = {ul[0], ul[1], ul[2], ul[3]};
  ((uint4*)wh)[fid] = vh;
  ((uint4*)wl)[fid] = vl;
}

// ---------------------------------------------------------------------------
// fgw_proj: 2 batches / block, 512 threads (8 waves, each 32 output cols).
// Per-batch x-tile: hi [0,16K) lo [16K,32K) within its 32KB half;
// rows 0-15 q / 16-31 r, row stride 512B, XOR swizzle ((row&7)<<4).
__global__ __launch_bounds__(512, 4)
void fgw_proj(const float* __restrict__ g_q,  const float* __restrict__ g_r,
              const unsigned short* __restrict__ wh,
              const unsigned short* __restrict__ wl,
              const float* __restrict__ g_b1, const float* __restrict__ g_b2,
              float* __restrict__ g_out)
{
  __shared__ __align__(16) float smemf[16896];   // 67,584 B -> 2 blocks/CU
  char* sm = (char*)smemf;
  const int bId0 = blockIdx.x * 2;
  const int tid  = threadIdx.x;
  const int lane = tid & 63, wid = tid >> 6;     // wid 0..7
  const int fr   = lane & 15, fg = lane >> 4;

  // ---- stage 2 batches as hi/lo bf16 (2048 float4-slots / 512 thr) ----
  #pragma unroll
  for (int j = 0; j < 4; ++j) {
    int idx = (j << 9) + tid;          // 0..2047
    int bb  = idx >> 10;
    int t   = idx & 1023;
    int r   = t >> 6;                  // row 0..15
    int sg  = t & 63;                  // float4 segment
    int off = ((sg << 3) ^ ((r & 7) << 4));
    char* xb = sm + bb * 32768;
    const float* xq = g_q + (size_t)(bId0 + bb) * 4096 + (r << 8) + (sg << 2);
    const float* xr = g_r + (size_t)(bId0 + bb) * 4096 + (r << 8) + (sg << 2);
    float4 v0 = *(const float4*)xq;
    float4 v1 = *(const float4*)xr;
    {
      unsigned short ha = f2bf(v0.x), hb = f2bf(v0.y), hc = f2bf(v0.z), hd = f2bf(v0.w);
      unsigned int* ph = (unsigned int*)(xb + r * 512 + off);
      ph[0] = (unsigned)ha | ((unsigned)hb << 16);
      ph[1] = (unsigned)hc | ((unsigned)hd << 16);
      unsigned short la = f2bf(v0.x - bf2f(ha)), lb = f2bf(v0.y - bf2f(hb));
      unsigned short lc = f2bf(v0.z - bf2f(hc)), ld = f2bf(v0.w - bf2f(hd));
      unsigned int* pl = (unsigned int*)(xb + 16384 + r * 512 + off);
      pl[0] = (unsigned)la | ((unsigned)lb << 16);
      pl[1] = (unsigned)lc | ((unsigned)ld << 16);
    }
    {
      int r2 = 16 + r;                 // same (row&7) -> same swizzle
      unsigned short ha = f2bf(v1.x), hb = f2bf(v1.y), hc = f2bf(v1.z), hd = f2bf(v1.w);
      unsigned int* ph = (unsigned int*)(xb + r2 * 512 + off);
      ph[0] = (unsigned)ha | ((unsigned)hb << 16);
      ph[1] = (unsigned)hc | ((unsigned)hd << 16);
      unsigned short la = f2bf(v1.x - bf2f(ha)), lb = f2bf(v1.y - bf2f(hb));
      unsigned short lc = f2bf(v1.z - bf2f(hc)), ld = f2bf(v1.w - bf2f(hd));
      unsigned int* pl = (unsigned int*)(xb + 16384 + r2 * 512 + off);
      pl[0] = (unsigned)la | ((unsigned)lb << 16);
      pl[1] = (unsigned)lc | ((unsigned)ld << 16);
    }
  }
  __syncthreads();

  // ---- two layers: out = act(X @ W^T + b); wave wid covers cols [32*wid,32*wid+32) ----
  for (int layer = 0; layer < 2; ++layer) {
    const f32x4 vzero = {0.f, 0.f, 0.f, 0.f};
    f32x4 acc[2][2][2];                  // [bb][mt][nt]
    #pragma unroll
    for (int bb = 0; bb < 2; ++bb)
      #pragma unroll
      for (int i = 0; i < 2; ++i)
        #pragma unroll
        for (int j = 0; j < 2; ++j) acc[bb][i][j] = vzero;

    const float* bl_ = layer ? g_b2 : g_b1;
    for (int ks = 0; ks < 8; ++ks) {
      const int koff = (ks << 6) + (fg << 4);
      const int aoff = koff ^ ((fr & 7) << 4);
      const size_t fb = ((((size_t)layer * 8 + ks) * 16 + (wid << 1)) * 64 + lane) * 8;
      s16x8 bh0  = *(const s16x8*)(wh + fb);
      s16x8 blo0 = *(const s16x8*)(wl + fb);
      s16x8 bh1  = *(const s16x8*)(wh + fb + 512);
      s16x8 blo1 = *(const s16x8*)(wl + fb + 512);
      #pragma unroll
      for (int bb = 0; bb < 2; ++bb) {
        char* xb = sm + bb * 32768;
        s16x8 ah0 = *(const s16x8*)(xb +          fr * 512       + aoff);
        s16x8 ah1 = *(const s16x8*)(xb +         (16 + fr) * 512 + aoff);
        s16x8 al0 = *(const s16x8*)(xb + 16384 +  fr * 512       + aoff);
        s16x8 al1 = *(const s16x8*)(xb + 16384 + (16 + fr) * 512 + aoff);
        acc[bb][0][0] = __builtin_amdgcn_mfma_f32_16x16x32_bf16(ah0, bh0,  acc[bb][0][0], 0, 0, 0);
        acc[bb][1][0] = __builtin_amdgcn_mfma_f32_16x16x32_bf16(ah1, bh0,  acc[bb][1][0], 0, 0, 0);
        acc[bb][0][0] = __builtin_amdgcn_mfma_f32_16x16x32_bf16(ah0, blo0, acc[bb][0][0], 0, 0, 0);
        acc[bb][1][0] = __builtin_amdgcn_mfma_f32_16x16x32_bf16(ah1, blo0, acc[bb][1][0], 0, 0, 0);
        acc[bb][0][0] = __builtin_amdgcn_mfma_f32_16x16x32_bf16(al0, bh0,  acc[bb][0][0], 0, 0, 0);
        acc[bb][1][0] = __builtin_amdgcn_mfma_f32_16x16x32_bf16(al1, bh0,  acc[bb][1][0], 0, 0, 0);
        acc[bb][0][1] = __builtin_amdgcn_mfma_f32_16x16x32_bf16(ah0, bh1,  acc[bb][0][1], 0, 0, 0);
        acc[bb][1][1] = __builtin_amdgcn_mfma_f32_16x16x32_bf16(ah1, bh1,  acc[bb][1][1], 0, 0, 0);
        acc[bb][0][1] = __builtin_amdgcn_mfma_f32_16x16x32_bf16(ah0, blo1, acc[bb][0][1], 0, 0, 0);
        acc[bb][1][1] = __builtin_amdgcn_mfma_f32_16x16x32_bf16(ah1, blo1, acc[bb][1][1], 0, 0, 0);
        acc[bb][0][1] = __builtin_amdgcn_mfma_f32_16x16x32_bf16(al0, bh1,  acc[bb][0][1], 0, 0, 0);
        acc[bb][1][1] = __builtin_amdgcn_mfma_f32_16x16x32_bf16(al1, bh1,  acc[bb][1][1], 0, 0, 0);
      }
    }
    __syncthreads();   // all x reads done before in-place overwrite

    float bv[2];
    #pragma unroll
    for (int nt = 0; nt < 2; ++nt) bv[nt] = bl_[(wid << 5) + (nt << 4) + fr];

    if (layer == 0) {
      #pragma unroll
      for (int bb = 0; bb < 2; ++bb) {
        char* xb = sm + bb * 32768;
        #pragma unroll
        for (int mt = 0; mt < 2; ++mt)
          #pragma unroll
          for (int nt = 0; nt < 2; ++nt)
            #pragma unroll
            for (int j = 0; j < 4; ++j) {
              float h = fmaxf(acc[bb][mt][nt][j] + bv[nt], 0.f);
              int row = (mt << 4) + (fg << 2) + j;
              int col = (wid << 5) + (nt << 4) + fr;
              int off = ((col << 1) ^ ((row & 7) << 4));
              unsigned short hh = f2bf(h);
              unsigned short hl = f2bf(h - bf2f(hh));
              *(unsigned short*)(xb +         row * 512 + off) = hh;
              *(unsigned short*)(xb + 16384 + row * 512 + off) = hl;
            }
      }
      __syncthreads();
    } else {
      // layer 2: norms (per-wave partials over its 32 cols) + write p hi/lo
      float* normL = smemf + 16384;    // [2][8][32] floats
      #pragma unroll
      for (int bb = 0; bb < 2; ++bb) {
        char* xb = sm + bb * 32768;
        #pragma unroll
        for (int mt = 0; mt < 2; ++mt)
          #pragma unroll
          for (int j = 0; j < 4; ++j) {
            float pv0 = acc[bb][mt][0][j] + bv[0];
            float pv1 = acc[bb][mt][1][j] + bv[1];
            float s = row16_sum(pv0 * pv0 + pv1 * pv1);
            int row = (mt << 4) + (fg << 2) + j;
            if (fr == 0) normL[(bb * 8 + wid) * 32 + row] = s;
            #pragma unroll
            for (int nt = 0; nt < 2; ++nt) {
              float pv = nt ? pv1 : pv0;
              int col = (wid << 5) + (nt << 4) + fr;
              int off = ((col << 1) ^ ((row & 7) << 4));
              unsigned short hh = f2bf(pv);
              unsigned short hl = f2bf(pv - bf2f(hh));
              *(unsigned short*)(xb +         row * 512 + off) = hh;
              *(unsigned short*)(xb + 16384 + row * 512 + off) = hl;
            }
          }
      }
      __syncthreads();
    }
  }

  // ---- G = pq @ pr^T: wave wid -> batch wid>>2, ksteps {2*(wid&3), +1} ----
  const f32x4 vz = {0.f, 0.f, 0.f, 0.f};
  f32x4 accG = vz;
  const int bbG = wid >> 2;
  {
    char* xb = sm + bbG * 32768;
    #pragma unroll
    for (int kk = 0; kk < 2; ++kk) {
      int ks   = ((wid & 3) << 1) + kk;
      int koff = (ks << 6) + (fg << 4);
      int aoff = koff ^ ((fr & 7) << 4);
      s16x8 aqh = *(const s16x8*)(xb +          fr * 512       + aoff);
      s16x8 aql = *(const s16x8*)(xb + 16384 +  fr * 512       + aoff);
      s16x8 brh = *(const s16x8*)(xb +         (16 + fr) * 512 + aoff);
      s16x8 brl = *(const s16x8*)(xb + 16384 + (16 + fr) * 512 + aoff);
      accG = __builtin_amdgcn_mfma_f32_16x16x32_bf16(aqh, brh, accG, 0, 0, 0);
      accG = __builtin_amdgcn_mfma_f32_16x16x32_bf16(aqh, brl, accG, 0, 0, 0);
      accG = __builtin_amdgcn_mfma_f32_16x16x32_bf16(aql, brh, accG, 0, 0, 0);
    }
  }
  __syncthreads();                       // all G-input reads complete
  float* Gp = smemf;                     // [2][4][256] overlays bytes [0,8192)
  #pragma unroll
  for (int j = 0; j < 4; ++j)
    Gp[(bbG * 4 + (wid & 3)) * 256 + ((fg << 2) + j) * 16 + fr] = accG[j];
  __syncthreads();

  // ---- C = sqrt(max(nq + nr - 2G, 1e-6)); threads 0-255 bb0, 256-511 bb1 ----
  {
    const int bbC = tid >> 8;
    const int t2  = tid & 255;
    const int tk  = t2 >> 4, tm = t2 & 15;
    const float* normL = smemf + 16384;
    float Gv = Gp[(bbC*4+0)*256 + tk*16 + tm] + Gp[(bbC*4+1)*256 + tk*16 + tm]
             + Gp[(bbC*4+2)*256 + tk*16 + tm] + Gp[(bbC*4+3)*256 + tk*16 + tm];
    float nq = 0.f, nr = 0.f;
    #pragma unroll
    for (int w = 0; w < 8; ++w) {
      nq += normL[(bbC*8+w)*32 + tk];
      nr += normL[(bbC*8+w)*32 + 16 + tm];
    }
    float d2 = nq + nr - 2.0f * Gv;
    g_out[OFF_C + (size_t)(bId0 + bbC) * 256 + t2] = sqrtf(fmaxf(d2, 1e-6f));
  }
}

// ---------------------------------------------------------------------------
// fgw_sink: 1 wave per batch, 4 waves/block, zero barriers.
// Lane layout: m = lane&15 (column), k_j = 4*(lane>>4)+j (4 rows per lane).
__global__ __launch_bounds__(256, 4)
void fgw_sink(const float* __restrict__ g_mq, const float* __restrict__ g_mr,
              const float* __restrict__ g_cq, const float* __restrict__ g_cr,
              const float* __restrict__ g_leps, float* __restrict__ g_out)
{
  __shared__ __align__(16) float sk[4 * 1408];
  const int tid  = threadIdx.x, lane = tid & 63, w = tid >> 6;
  const int batch = blockIdx.x * 4 + w;
  const int m = lane & 15, g = lane >> 4;
  float* L     = sk + w * 1408;
  float* SqL   = L;        float* SrL   = L + 320;
  float* TtL   = L + 640;  float* M1L   = L + 960;
  float* lmuL  = L + 1280; float* muL   = L + 1296;
  float* cqxL  = L + 1312; float* cqyL  = L + 1328;
  float* crxL  = L + 1344; float* cryL  = L + 1360;
  float* trowL = L + 1376; float* tcolL = L + 1392;

  // ---- masks -> mu/nu (per-lane index m), redistribute to k_j via LDS ----
  float mqv = g_mq[(size_t)batch * 16 + m];
  float mrv = g_mr[(size_t)batch * 16 + m];
  float mu_m = mqv / (row16_sum(mqv) + 1e-8f);
  float nu_m = mrv / (row16_sum(mrv) + 1e-8f);
  float lmu_m = __logf(fmaxf(mu_m, 1e-8f));
  float lnu_m = __logf(fmaxf(nu_m, 1e-8f));
  float cqx_m = g_cq[(size_t)batch * 32 + 2 * m];
  float cqy_m = g_cq[(size_t)batch * 32 + 2 * m + 1];
  float crx_m = g_cr[(size_t)batch * 32 + 2 * m];
  float cry_m = g_cr[(size_t)batch * 32 + 2 * m + 1];
  if (g == 0) {
    lmuL[m] = lmu_m;  muL[m] = mu_m;
    cqxL[m] = cqx_m;  cqyL[m] = cqy_m;
    crxL[m] = crx_m;  cryL[m] = cry_m;
  }
  f32x4 lmu_j = *(const f32x4*)(lmuL + 4 * g);
  f32x4 mu_j  = *(const f32x4*)(muL  + 4 * g);
  f32x4 cqxj  = *(const f32x4*)(cqxL + 4 * g);
  f32x4 cqyj  = *(const f32x4*)(cqyL + 4 * g);
  f32x4 crxj  = *(const f32x4*)(crxL + 4 * g);
  f32x4 cryj  = *(const f32x4*)(cryL + 4 * g);

  // ---- Sq/Sr (rows k_j, col m); Sq2/Sr2 kept in registers ----
  float Sq2r[4], Sr2r[4];
  #pragma unroll
  for (int j = 0; j < 4; ++j) {
    float dx = cqxj[j] - cqx_m, dy = cqyj[j] - cqy_m;
    float d2 = fmaxf(dx * dx + dy * dy, 1e-6f);
    SqL[(4 * g + j) * 20 + m] = sqrtf(d2);
    Sq2r[j] = d2;
    float ex = crxj[j] - crx_m, ey = cryj[j] - cry_m;
    float e2 = fmaxf(ex * ex + ey * ey, 1e-6f);
    SrL[(4 * g + j) * 20 + m] = sqrtf(e2);
    Sr2r[j] = e2;
  }

  // ---- C, eps, T init ----
  float C_[4];
  const float* Cp = g_out + OFF_C + (size_t)batch * 256;
  #pragma unroll
  for (int j = 0; j < 4; ++j) C_[j] = Cp[(4 * g + j) * 16 + m];
  float eps = fminf(fmaxf(__expf(g_leps[0]), 0.01f), 0.5f);
  const float inv_eps = 1.0f / eps;
  const float rho = 0.1f / (0.1f + eps);
  float rlmu[4];
  #pragma unroll
  for (int j = 0; j < 4; ++j) rlmu[j] = rho * lmu_j[j];
  const float rlnu = rho * lnu_m;
  float T_[4];
  #pragma unroll
  for (int j = 0; j < 4; ++j) T_[j] = mu_j[j] * nu_m;

  float Cf[4], logK[4], KM[4], Mx[4], u_[4], v = 0.f;

  // ---- 5 outer FGW iterations ----
  for (int it = 0; it < 5; ++it) {
    float trow_j[4];
    #pragma unroll
    for (int j = 0; j < 4; ++j) trow_j[j] = row16_sum(T_[j]);
    float tc = xor32_add(xor16_add(T_[0] + T_[1] + T_[2] + T_[3]));
    if (m == 0) { f32x4 tv = {trow_j[0], trow_j[1], trow_j[2], trow_j[3]};
                  *(f32x4*)(trowL + 4 * g) = tv; }
    if (g == 0) tcolL[m] = tc;
    { f32x4 tv = {T_[0], T_[1], T_[2], T_[3]};
      *(f32x4*)(TtL + m * 20 + 4 * g) = tv; }

    float trow_m = trowL[m];
    float t1_[4];
    #pragma unroll
    for (int j = 0; j < 4; ++j) t1_[j] = row16_sum(Sq2r[j] * trow_m);
    f32x4 tcv = *(const f32x4*)(tcolL + 4 * g);
    float p2 = tcv[0] * Sr2r[0] + tcv[1] * Sr2r[1] + tcv[2] * Sr2r[2] + tcv[3] * Sr2r[3];
    float t2_ = xor32_add(xor16_add(p2));

    float M1r[4] = {0.f, 0.f, 0.f, 0.f};
    #pragma unroll
    for (int l = 0; l < 16; ++l) {
      f32x4 t4 = *(const f32x4*)(TtL + l * 20 + 4 * g);
      float srv = SrL[l * 20 + m];
      M1r[0] += t4[0] * srv; M1r[1] += t4[1] * srv;
      M1r[2] += t4[2] * srv; M1r[3] += t4[3] * srv;
    }
    #pragma unroll
    for (int j = 0; j < 4; ++j) M1L[(4 * g + j) * 20 + m] = M1r[j];
    float t3_[4] = {0.f, 0.f, 0.f, 0.f};
    #pragma unroll
    for (int l = 0; l < 16; ++l) {
      f32x4 sq4 = *(const f32x4*)(SqL + l * 20 + 4 * g);
      float m1v = M1L[l * 20 + m];
      t3_[0] += sq4[0] * m1v; t3_[1] += sq4[1] * m1v;
      t3_[2] += sq4[2] * m1v; t3_[3] += sq4[3] * m1v;
    }

    #pragma unroll
    for (int j = 0; j < 4; ++j) {
      float lgw = t1_[j] + t2_ - 2.0f * t3_[j];
      Cf[j]   = 0.5f * C_[j] + 0.5f * lgw;
      logK[j] = -inv_eps * Cf[j];
      Mx[j]   = row16_max(logK[j]);     // static row shift (underflow-safe)
      KM[j]   = logK[j] - Mx[j];
    }

    v = 0.f;
    #pragma unroll 1
    for (int s = 0; s < 10; ++s) {
      #pragma unroll
      for (int j = 0; j < 4; ++j) {
        float sj = row16_sum(__expf(KM[j] + v));
        u_[j] = rlmu[j] - rho * (Mx[j] + __logf(sj));
      }
      float x0 = logK[0] + u_[0], x1 = logK[1] + u_[1];
      float x2 = logK[2] + u_[2], x3 = logK[3] + u_[3];
      float mx = fmaxf(fmaxf(x0, x1), fmaxf(x2, x3));
      mx = xor32_max(xor16_max(mx));
      float ss = __expf(x0 - mx) + __expf(x1 - mx) + __expf(x2 - mx) + __expf(x3 - mx);
      ss = xor32_add(xor16_add(ss));
      v = rlnu - rho * (mx + __logf(ss));
    }
    #pragma unroll
    for (int j = 0; j < 4; ++j) T_[j] = __expf(u_[j] + logK[j] + v);
  }

  // ---- outputs ----
  float cp = T_[0] * Cf[0] + T_[1] * Cf[1] + T_[2] * Cf[2] + T_[3] * Cf[3];
  cp = xor32_add(xor16_add(row16_sum(cp)));
  float* To = g_out + OFF_T + (size_t)batch * 256;
  #pragma unroll
  for (int j = 0; j < 4; ++j) To[(4 * g + j) * 16 + m] = T_[j];
  if (lane == 0) {
    g_out[batch] = 1.0f / (1.0f + __expf(cp));   // sigmoid(-cost)
    g_out[OFF_CST + batch] = cp;
  }
}

extern "C" void kernel_launch(void* const* d_in, const int* in_sizes, int n_in,
                              void* d_out, int out_size, void* d_ws, size_t ws_size,
                              hipStream_t stream) {
  (void)in_sizes; (void)n_in; (void)out_size; (void)ws_size;
  unsigned int*   wh32 = (unsigned int*)d_ws;
  unsigned int*   wl32 = wh32 + 65536;                 // 262,144 B each
  unsigned short* wh   = (unsigned short*)wh32;
  unsigned short* wl   = (unsigned short*)wl32;

  prep_w<<<dim3(64), dim3(256), 0, stream>>>(
      (const float*)d_in[6], (const float*)d_in[8], wh32, wl32);
  fgw_proj<<<dim3(4096), dim3(512), 0, stream>>>(
      (const float*)d_in[0], (const float*)d_in[1], wh, wl,
      (const float*)d_in[7], (const float*)d_in[9], (float*)d_out);
  fgw_sink<<<dim3(2048), dim3(256), 0, stream>>>(
      (const float*)d_in[2], (const float*)d_in[3],
      (const float*)d_in[4], (const float*)d_in[5],
      (const float*)d_in[10], (float*)d_out);
}